// Round 5
// baseline (201.757 us; speedup 1.0000x reference)
//
#include <hip/hip_runtime.h>
#include <stdint.h>

typedef __attribute__((ext_vector_type(4)))  int   intx4;
typedef __attribute__((ext_vector_type(8)))  int   intx8;
typedef __attribute__((ext_vector_type(16))) float floatx16;

#define GLL16(gp, lp)                                                               \
    __builtin_amdgcn_global_load_lds((const __attribute__((address_space(1))) unsigned int*)(gp), \
                                     (__attribute__((address_space(3))) unsigned int*)(lp), 16, 0, 0)
#define GLL4(gp, lp)                                                                \
    __builtin_amdgcn_global_load_lds((const __attribute__((address_space(1))) unsigned int*)(gp), \
                                     (__attribute__((address_space(3))) unsigned int*)(lp), 4, 0, 0)

// ---------------------------------------------------------------------------
// RTE onto the e2m1 grid {0,.5,1,1.5,2,3,4,6} -> code 0..7 (ties-to-even,
// matches ref searchsorted+tie-fix). Sign -> bit 3. (proven)
// ---------------------------------------------------------------------------
__device__ __forceinline__ uint32_t enc1(float xv, float inv) {
    float a = fminf(fabsf(xv) * inv, 6.0f);
    int e;
    if (a < 2.0f)      e = (int)rintf(a + a);          // 0,.5,1,1.5,2 -> 0..4
    else if (a < 4.0f) e = (int)rintf(a) + 2;          // 2,3,4        -> 4..6
    else               e = (int)rintf(a * 0.5f) + 4;   // 4,6          -> 6,7
    return (uint32_t)e | ((__float_as_uint(xv) >> 28) & 8u);
}

// ---------------------------------------------------------------------------
// Kernel 1: quantize x (proven rounds 1-4). All accesses coalesced; scales
// to NATURAL layout xs[m*kbpr+kb].
// ---------------------------------------------------------------------------
__global__ __launch_bounds__(256) void quant_x_kernel(const float* __restrict__ x,
                                                      uint32_t* __restrict__ xq,
                                                      uint8_t* __restrict__ xs) {
    const int gl = blockIdx.x * 256 + threadIdx.x;          // lane over M*K/4
    const float4 v = ((const float4*)x)[gl];
    float m = fmaxf(fmaxf(fabsf(v.x), fabsf(v.y)), fmaxf(fabsf(v.z), fabsf(v.w)));
    m = fmaxf(m, __shfl_xor(m, 1));
    m = fmaxf(m, __shfl_xor(m, 2));
    m = fmaxf(m, __shfl_xor(m, 4));                         // 8-lane group = 1 MX block
    const unsigned ef = __float_as_uint(m) >> 23;
    const unsigned code = (ef < 3u) ? 1u : (ef - 2u);       // FLOOR scale, clamped
    const float inv = __uint_as_float((254u - code) << 23); // exact 2^(127-code)
    const uint32_t p = enc1(v.x, inv)        | (enc1(v.y, inv) << 4)
                     | (enc1(v.z, inv) << 8) | (enc1(v.w, inv) << 12);
    ((uint16_t*)xq)[gl] = (uint16_t)p;                      // coalesced 2 B/lane
    if ((gl & 7) == 0) xs[gl >> 3] = (uint8_t)code;         // coalesced byte/8 lanes
}

// ---------------------------------------------------------------------------
// Kernel 2: merged repack (proven rounds 1-4).
// ---------------------------------------------------------------------------
__global__ __launch_bounds__(256) void repack_kernel(const int* __restrict__ wp,
                                                     uint32_t* __restrict__ wrep,
                                                     int n4w,
                                                     const int* __restrict__ wsc,
                                                     uint32_t* __restrict__ ws,
                                                     int n4s) {
    const int t = blockIdx.x * 256 + threadIdx.x;
    if (t < n4w) {
        const int4 p = ((const int4*)wp)[t];
        wrep[t] = (uint32_t)(p.x & 0xFF) | ((uint32_t)(p.y & 0xFF) << 8)
                | ((uint32_t)(p.z & 0xFF) << 16) | ((uint32_t)(p.w & 0xFF) << 24);
    } else if (t - n4w < n4s) {
        const int i = t - n4w;
        const int4 p = ((const int4*)wsc)[i];
        ws[i] = (uint32_t)(p.x & 0xFF) | ((uint32_t)(p.y & 0xFF) << 8)
              | ((uint32_t)(p.z & 0xFF) << 16) | ((uint32_t)(p.w & 0xFF) << 24);
    }
}

// ---------------------------------------------------------------------------
// Kernel 2c: transpose both scale arrays (proven round 4).
// ---------------------------------------------------------------------------
__global__ __launch_bounds__(256) void tpose_s_kernel(const uint8_t* __restrict__ nat,
                                                      uint8_t* __restrict__ xs_t,
                                                      uint8_t* __restrict__ ws_t,
                                                      int R, int Ck) {
    __shared__ uint8_t raw[128 * 32];
    const int r0 = blockIdx.x * 128;
    const int c0 = blockIdx.y * 32;
    const int t = threadIdx.x;
    {
        const int r = t >> 1, hf = t & 1;
        const uint4 v = *(const uint4*)(nat + (size_t)(r0 + r) * Ck + c0 + hf * 16);
        *(uint4*)(raw + r * 32 + hf * 16) = v;
    }
    __syncthreads();
    const int c = t >> 3, q = t & 7;
    uint32_t d[4];
#pragma unroll
    for (int j = 0; j < 4; ++j) {
        const int mb = q * 16 + j * 4;
        d[j] = (uint32_t)raw[(mb + 0) * 32 + c]
             | ((uint32_t)raw[(mb + 1) * 32 + c] << 8)
             | ((uint32_t)raw[(mb + 2) * 32 + c] << 16)
             | ((uint32_t)raw[(mb + 3) * 32 + c] << 24);
    }
    uint8_t* outp = (r0 < R) ? (xs_t + (size_t)(c0 + c) * R + r0)
                             : (ws_t + (size_t)(c0 + c) * R + (r0 - R));
    *(uint4*)(outp + q * 16) = make_uint4(d[0], d[1], d[2], d[3]);
}

// ---------------------------------------------------------------------------
// Kernel 3: MXFP4 GEMM, 128x128 tile, BK=128, 4 waves x (2x2)
// v_mfma_scale_f32_32x32x64_f8f6f4 (fmt 4 = fp4 e2m1).
//
// Round-5 change: prefetch depth P=2 with TRIPLE-buffered LDS and counted
// vmcnt(10) + raw s_barrier (no vmcnt(0) drain). Chunk c's 5 loads are
// issued 2 iterations (~1200 cy) before use -> ~900 cy HBM latency fully
// hidden; the per-chunk wait becomes a no-op in steady state. LDS 52 KB ->
// 3 blocks/CU. Round-1's P=1 was neutral (560 cy < latency + polluted by
// scale-gather); P=2 crosses the latency threshold.
//
// Kept proven: swizzle slot = kp ^ ((r>>1)&3) (conflicts 12.58M->4.19M),
// coalesced transposed-scale staging (one 512-B GLL4 per chunk).
// ---------------------------------------------------------------------------
__global__ __launch_bounds__(256) void gemm_mx_kernel(const uint8_t* __restrict__ Apk,
                                                      const uint8_t* __restrict__ Bpk,
                                                      const uint8_t* __restrict__ AsT,
                                                      const uint8_t* __restrict__ BsT,
                                                      float* __restrict__ C,
                                                      int M, int N, int K) {
    __shared__ __align__(16) uint8_t sA[3][8192];   // 128 rows x 64 B, 3 bufs
    __shared__ __align__(16) uint8_t sB[3][8192];
    __shared__ __align__(16) uint8_t sS[3][1024];   // [A kb0..3][row] | [B kb0..3][row]

    const int tid = threadIdx.x;
    const int bm0 = blockIdx.y << 7;
    const int bn0 = blockIdx.x << 7;
    const int wave = tid >> 6;
    const int lane = tid & 63;
    const int wm = (wave >> 1) << 6;
    const int wn = (wave & 1) << 6;
    const int row = lane & 31;
    const int h = lane >> 5;
    const int Kb = K >> 1;                          // packed bytes per row

    // data staging: slot s at LDS [16s,16s+16); content = row s>>2,
    // piece p = (s&3) ^ ((r>>1)&3)  (XOR involution, 8-position spread)
    const int s0 = tid, s1 = tid + 256;
    const int r0 = s0 >> 2, p0 = (s0 & 3) ^ ((r0 >> 1) & 3);
    const int r1 = s1 >> 2, p1 = (s1 & 3) ^ ((r1 >> 1) & 3);
    const uint8_t* Ag0 = Apk + (size_t)(bm0 + r0) * Kb + p0 * 16;
    const uint8_t* Ag1 = Apk + (size_t)(bm0 + r1) * Kb + p1 * 16;
    const uint8_t* Bg0 = Bpk + (size_t)(bn0 + r0) * Kb + p0 * 16;
    const uint8_t* Bg1 = Bpk + (size_t)(bn0 + r1) * Kb + p1 * 16;

    // scale staging (coalesced, transposed arrays): waves 0-1 -> A, 2-3 -> B.
    const int st = tid & 127;
    const int sj = st >> 5, si = st & 31;
    const uint8_t* Sg = (tid < 128) ? (AsT + (size_t)sj * M + bm0 + si * 4)
                                    : (BsT + (size_t)sj * N + bn0 + si * 4);
    const int sloff = ((tid < 128) ? 0 : 512) + st * 4;
    const size_t sAdv = (size_t)4 * (size_t)((tid < 128) ? M : N);

    floatx16 acc[2][2];
#pragma unroll
    for (int a = 0; a < 2; ++a)
#pragma unroll
        for (int b = 0; b < 2; ++b)
#pragma unroll
            for (int r = 0; r < 16; ++r) acc[a][b][r] = 0.f;

    const int nchunk = K >> 7;                      // 32
    const int ar0 = wm + row, ar1 = wm + 32 + row;
    const int br0 = wn + row, br1 = wn + 32 + row;

    // 5 VMEM instructions per wave per STAGE (4x GLL16 + 1x GLL4)
    auto STAGE = [&](int bf, int c) {
        const size_t koff = (size_t)c << 6;         // 64 B per chunk
        GLL16(Ag0 + koff, &sA[bf][s0 * 16]);
        GLL16(Ag1 + koff, &sA[bf][s1 * 16]);
        GLL16(Bg0 + koff, &sB[bf][s0 * 16]);
        GLL16(Bg1 + koff, &sB[bf][s1 * 16]);
        GLL4(Sg + (size_t)c * sAdv, &sS[bf][sloff]);
    };

    auto COMPUTE = [&](int bf) {
        const uint8_t* cA = sA[bf];
        const uint8_t* cB = sB[bf];
        const uint8_t* cS = sS[bf];
#pragma unroll
        for (int s = 0; s < 2; ++s) {
            const int kp = 2 * s + h;               // 16B piece index 0..3
            intx4 a4[2], b4[2];
            int sa[2], sb[2];
            a4[0] = *(const intx4*)(cA + ar0 * 64 + ((kp ^ ((ar0 >> 1) & 3)) << 4));
            a4[1] = *(const intx4*)(cA + ar1 * 64 + ((kp ^ ((ar1 >> 1) & 3)) << 4));
            b4[0] = *(const intx4*)(cB + br0 * 64 + ((kp ^ ((br0 >> 1) & 3)) << 4));
            b4[1] = *(const intx4*)(cB + br1 * 64 + ((kp ^ ((br1 >> 1) & 3)) << 4));
            sa[0] = cS[kp * 128 + ar0];
            sa[1] = cS[kp * 128 + ar1];
            sb[0] = cS[512 + kp * 128 + br0];
            sb[1] = cS[512 + kp * 128 + br1];
#pragma unroll
            for (int mt = 0; mt < 2; ++mt)
#pragma unroll
                for (int nt = 0; nt < 2; ++nt) {
                    intx8 a8 = {a4[mt][0], a4[mt][1], a4[mt][2], a4[mt][3], 0, 0, 0, 0};
                    intx8 b8 = {b4[nt][0], b4[nt][1], b4[nt][2], b4[nt][3], 0, 0, 0, 0};
                    acc[mt][nt] = __builtin_amdgcn_mfma_scale_f32_32x32x64_f8f6f4(
                        a8, b8, acc[mt][nt], 4, 4, 0, sa[mt], 0, sb[nt]);
                }
        }
    };

    // prologue: chunks 0,1 in flight (10 outstanding VMEM/wave)
    STAGE(0, 0);
    STAGE(1, 1);

    int i0 = 0, i1 = 1, i2 = 2;                     // compute buf, next, stage buf
    for (int c = 0; c < nchunk; ++c) {
        // barrier A: all waves done computing buf i2 (= chunk c-1's buffer)
        // before this wave's STAGE overwrites it.
        __builtin_amdgcn_s_barrier();
        asm volatile("" ::: "memory");
        if (c + 2 < nchunk) STAGE(i2, c + 2);
        // counted wait: chunk c's 5 loads done (own wave); then barrier B
        // publishes all waves' chunk-c data. Never drains the prefetches.
        if (c < nchunk - 2)      asm volatile("s_waitcnt vmcnt(10)" ::: "memory");
        else if (c == nchunk - 2) asm volatile("s_waitcnt vmcnt(5)" ::: "memory");
        else                      asm volatile("s_waitcnt vmcnt(0)" ::: "memory");
        __builtin_amdgcn_s_barrier();
        asm volatile("" ::: "memory");
        COMPUTE(i0);
        const int t = i0; i0 = i1; i1 = i2; i2 = t; // rotate buffers
    }

    // C/D layout (32x32): col = lane&31, row = (reg&3) + 8*(reg>>2) + 4*(lane>>5)
#pragma unroll
    for (int mt = 0; mt < 2; ++mt)
#pragma unroll
        for (int nt = 0; nt < 2; ++nt) {
            const int col = bn0 + wn + nt * 32 + row;
#pragma unroll
            for (int g = 0; g < 4; ++g) {
                const int rw = bm0 + wm + mt * 32 + 8 * g + 4 * h;
#pragma unroll
                for (int q = 0; q < 4; ++q)
                    C[(size_t)(rw + q) * N + col] = acc[mt][nt][4 * g + q];
            }
        }
}

// ---------------------------------------------------------------------------
extern "C" void kernel_launch(void* const* d_in, const int* in_sizes, int n_in,
                              void* d_out, int out_size, void* d_ws, size_t ws_size,
                              hipStream_t stream) {
    const float* x = (const float*)d_in[0];
    const int* wp = (const int*)d_in[1];
    const int* wsc = (const int*)d_in[2];
    float* out = (float*)d_out;

    const int K = 4096;
    const int M = in_sizes[0] / K;            // 4096
    const int N = (in_sizes[1] * 2) / K;      // 4096
    const int kbpr = K / 32;                  // 128
    const int npack = N * K / 2;              // weight packed bytes

    uint32_t* xq   = (uint32_t*)d_ws;                                  // 8 MiB
    uint8_t*  xs   = (uint8_t*)d_ws + (size_t)M * K / 2;               // 512 KiB [m][kb]
    uint8_t*  ws   = xs + (size_t)M * kbpr;                            // 512 KiB [n][kb]
    uint32_t* wrep = (uint32_t*)(ws + (size_t)N * kbpr);               // 8 MiB
    uint8_t*  xs_t = (uint8_t*)(wrep + (size_t)npack / 4);             // 512 KiB [kb][m]
    uint8_t*  ws_t = xs_t + (size_t)M * kbpr;                          // 512 KiB [kb][n]

    const int n4w = npack / 4;
    const int n4s = (N * kbpr) / 4;

    quant_x_kernel<<<(M * K / 4) / 256, 256, 0, stream>>>(x, xq, xs);
    repack_kernel<<<(n4w + n4s + 255) / 256, 256, 0, stream>>>(wp, wrep, n4w,
                                                               wsc, (uint32_t*)ws, n4s);
    dim3 tg(2 * M / 128, kbpr / 32);
    tpose_s_kernel<<<tg, 256, 0, stream>>>(xs, xs_t, ws_t, M, kbpr);

    dim3 grid(N / 128, M / 128);
    gemm_mx_kernel<<<grid, 256, 0, stream>>>((const uint8_t*)xq, (const uint8_t*)wrep,
                                             xs_t, ws_t, out, M, N, K);
}

// Round 6
// 192.287 us; speedup vs baseline: 1.0492x; 1.0492x over previous
//
#include <hip/hip_runtime.h>
#include <stdint.h>

typedef __attribute__((ext_vector_type(4)))  int   intx4;
typedef __attribute__((ext_vector_type(8)))  int   intx8;
typedef __attribute__((ext_vector_type(16))) float floatx16;

#define GLL16(gp, lp)                                                               \
    __builtin_amdgcn_global_load_lds((const __attribute__((address_space(1))) unsigned int*)(gp), \
                                     (__attribute__((address_space(3))) unsigned int*)(lp), 16, 0, 0)
#define GLL4(gp, lp)                                                                \
    __builtin_amdgcn_global_load_lds((const __attribute__((address_space(1))) unsigned int*)(gp), \
                                     (__attribute__((address_space(3))) unsigned int*)(lp), 4, 0, 0)

// ---------------------------------------------------------------------------
// RTE onto the e2m1 grid {0,.5,1,1.5,2,3,4,6} -> code 0..7 (ties-to-even,
// matches ref searchsorted+tie-fix). Sign -> bit 3. (proven)
// ---------------------------------------------------------------------------
__device__ __forceinline__ uint32_t enc1(float xv, float inv) {
    float a = fminf(fabsf(xv) * inv, 6.0f);
    int e;
    if (a < 2.0f)      e = (int)rintf(a + a);          // 0,.5,1,1.5,2 -> 0..4
    else if (a < 4.0f) e = (int)rintf(a) + 2;          // 2,3,4        -> 4..6
    else               e = (int)rintf(a * 0.5f) + 4;   // 4,6          -> 6,7
    return (uint32_t)e | ((__float_as_uint(xv) >> 28) & 8u);
}

// ---------------------------------------------------------------------------
// Kernel 1: quantize x (proven rounds 1-5). All accesses coalesced; scales
// to NATURAL layout xs[m*kbpr+kb].
// ---------------------------------------------------------------------------
__global__ __launch_bounds__(256) void quant_x_kernel(const float* __restrict__ x,
                                                      uint32_t* __restrict__ xq,
                                                      uint8_t* __restrict__ xs) {
    const int gl = blockIdx.x * 256 + threadIdx.x;          // lane over M*K/4
    const float4 v = ((const float4*)x)[gl];
    float m = fmaxf(fmaxf(fabsf(v.x), fabsf(v.y)), fmaxf(fabsf(v.z), fabsf(v.w)));
    m = fmaxf(m, __shfl_xor(m, 1));
    m = fmaxf(m, __shfl_xor(m, 2));
    m = fmaxf(m, __shfl_xor(m, 4));                         // 8-lane group = 1 MX block
    const unsigned ef = __float_as_uint(m) >> 23;
    const unsigned code = (ef < 3u) ? 1u : (ef - 2u);       // FLOOR scale, clamped
    const float inv = __uint_as_float((254u - code) << 23); // exact 2^(127-code)
    const uint32_t p = enc1(v.x, inv)        | (enc1(v.y, inv) << 4)
                     | (enc1(v.z, inv) << 8) | (enc1(v.w, inv) << 12);
    ((uint16_t*)xq)[gl] = (uint16_t)p;                      // coalesced 2 B/lane
    if ((gl & 7) == 0) xs[gl >> 3] = (uint8_t)code;         // coalesced byte/8 lanes
}

// ---------------------------------------------------------------------------
// Kernel 2: merged repack (proven rounds 1-5).
// ---------------------------------------------------------------------------
__global__ __launch_bounds__(256) void repack_kernel(const int* __restrict__ wp,
                                                     uint32_t* __restrict__ wrep,
                                                     int n4w,
                                                     const int* __restrict__ wsc,
                                                     uint32_t* __restrict__ ws,
                                                     int n4s) {
    const int t = blockIdx.x * 256 + threadIdx.x;
    if (t < n4w) {
        const int4 p = ((const int4*)wp)[t];
        wrep[t] = (uint32_t)(p.x & 0xFF) | ((uint32_t)(p.y & 0xFF) << 8)
                | ((uint32_t)(p.z & 0xFF) << 16) | ((uint32_t)(p.w & 0xFF) << 24);
    } else if (t - n4w < n4s) {
        const int i = t - n4w;
        const int4 p = ((const int4*)wsc)[i];
        ws[i] = (uint32_t)(p.x & 0xFF) | ((uint32_t)(p.y & 0xFF) << 8)
              | ((uint32_t)(p.z & 0xFF) << 16) | ((uint32_t)(p.w & 0xFF) << 24);
    }
}

// ---------------------------------------------------------------------------
// Kernel 2c: transpose both scale arrays (proven round 4).
// ---------------------------------------------------------------------------
__global__ __launch_bounds__(256) void tpose_s_kernel(const uint8_t* __restrict__ nat,
                                                      uint8_t* __restrict__ xs_t,
                                                      uint8_t* __restrict__ ws_t,
                                                      int R, int Ck) {
    __shared__ uint8_t raw[128 * 32];
    const int r0 = blockIdx.x * 128;
    const int c0 = blockIdx.y * 32;
    const int t = threadIdx.x;
    {
        const int r = t >> 1, hf = t & 1;
        const uint4 v = *(const uint4*)(nat + (size_t)(r0 + r) * Ck + c0 + hf * 16);
        *(uint4*)(raw + r * 32 + hf * 16) = v;
    }
    __syncthreads();
    const int c = t >> 3, q = t & 7;
    uint32_t d[4];
#pragma unroll
    for (int j = 0; j < 4; ++j) {
        const int mb = q * 16 + j * 4;
        d[j] = (uint32_t)raw[(mb + 0) * 32 + c]
             | ((uint32_t)raw[(mb + 1) * 32 + c] << 8)
             | ((uint32_t)raw[(mb + 2) * 32 + c] << 16)
             | ((uint32_t)raw[(mb + 3) * 32 + c] << 24);
    }
    uint8_t* outp = (r0 < R) ? (xs_t + (size_t)(c0 + c) * R + r0)
                             : (ws_t + (size_t)(c0 + c) * R + (r0 - R));
    *(uint4*)(outp + q * 16) = make_uint4(d[0], d[1], d[2], d[3]);
}

// ---------------------------------------------------------------------------
// Kernel 3: MXFP4 GEMM, 128x128 tile, 4 waves x (2x2)
// v_mfma_scale_f32_32x32x64_f8f6f4 (fmt 4 = fp4 e2m1).
//
// Round-6 single variable: BK 128 -> 256. Halves the per-chunk barrier
// drains (32 -> 16) while keeping 4 blocks/CU (LDS 34 KB < 160/4), which
// rounds 1/5 proved is the binding constraint. Per chunk: 8 GLL16 + 2 GLL4
// per wave, 16 MFMAs per wave. Swizzle generalizes: within-row slot w holds
// piece p = w ^ (r&7) -> fixed-kp reads walk all 8 16-B positions per 8
// rows (same 4-way floor as round 4's 4.19M conflicts).
//
// Proven kept: single buffer + 2x __syncthreads (occupancy > pipelining),
// coalesced transposed-scale staging (now 2 GLL4/chunk: slices 0-3, 4-7).
// ---------------------------------------------------------------------------
__global__ __launch_bounds__(256) void gemm_mx_kernel(const uint8_t* __restrict__ Apk,
                                                      const uint8_t* __restrict__ Bpk,
                                                      const uint8_t* __restrict__ AsT,
                                                      const uint8_t* __restrict__ BsT,
                                                      float* __restrict__ C,
                                                      int M, int N, int K) {
    __shared__ __align__(16) uint8_t sA[16384];   // 128 rows x 128 B
    __shared__ __align__(16) uint8_t sB[16384];
    __shared__ __align__(16) uint8_t sS[2048];    // [A kb0..7][row] | [B kb0..7][row]

    const int tid = threadIdx.x;
    const int bm0 = blockIdx.y << 7;
    const int bn0 = blockIdx.x << 7;
    const int wave = tid >> 6;
    const int lane = tid & 63;
    const int wm = (wave >> 1) << 6;
    const int wn = (wave & 1) << 6;
    const int row = lane & 31;
    const int h = lane >> 5;
    const int Kb = K >> 1;                        // packed bytes per row (2048)

    // data staging: 1024 slots/tile (128 rows x 8 pieces), 4 slots/thread.
    // slot s: row r = s>>3, within-row slot w = s&7, content piece
    // p = w ^ (r&7)  (XOR involution, full 8-position spread)
    const uint8_t* Ag[4];
    const uint8_t* Bg[4];
#pragma unroll
    for (int i = 0; i < 4; ++i) {
        const int s = tid + 256 * i;
        const int r = s >> 3;
        const int p = (s & 7) ^ (r & 7);
        Ag[i] = Apk + (size_t)(bm0 + r) * Kb + p * 16;
        Bg[i] = Bpk + (size_t)(bn0 + r) * Kb + p * 16;
    }

    // scale staging (coalesced, transposed arrays): waves 0-1 -> A, 2-3 -> B.
    // Chunk c covers kb slices 8c..8c+7; GLL4 #1 stages slices 0-3, #2 4-7.
    const int st = tid & 127;
    const int sj = st >> 5, si = st & 31;
    const size_t sR = (size_t)((tid < 128) ? M : N);
    const uint8_t* Sg1 = ((tid < 128) ? (AsT + (size_t)sj * M + bm0)
                                      : (BsT + (size_t)sj * N + bn0)) + si * 4;
    const uint8_t* Sg2 = Sg1 + 4 * sR;
    const size_t sAdv = 8 * sR;
    const int soff = ((tid < 128) ? 0 : 1024) + st * 4;

    floatx16 acc[2][2];
#pragma unroll
    for (int a = 0; a < 2; ++a)
#pragma unroll
        for (int b = 0; b < 2; ++b)
#pragma unroll
            for (int r = 0; r < 16; ++r) acc[a][b][r] = 0.f;

    const int nchunk = K >> 8;                    // 16
    const int ar0 = wm + row, ar1 = wm + 32 + row;
    const int br0 = wn + row, br1 = wn + 32 + row;

    for (int c = 0; c < nchunk; ++c) {
        __syncthreads();
        const size_t koff = (size_t)c << 7;       // 128 B per chunk
#pragma unroll
        for (int i = 0; i < 4; ++i) GLL16(Ag[i] + koff, sA + (tid + 256 * i) * 16);
#pragma unroll
        for (int i = 0; i < 4; ++i) GLL16(Bg[i] + koff, sB + (tid + 256 * i) * 16);
        GLL4(Sg1 + (size_t)c * sAdv, sS + soff);
        GLL4(Sg2 + (size_t)c * sAdv, sS + soff + 512);
        __syncthreads();

#pragma unroll
        for (int s = 0; s < 4; ++s) {
            const int kp = 2 * s + h;             // 16B piece / MX-block index 0..7
            intx4 a4[2], b4[2];
            int sa[2], sb[2];
            a4[0] = *(const intx4*)(sA + ar0 * 128 + ((kp ^ (ar0 & 7)) << 4));
            a4[1] = *(const intx4*)(sA + ar1 * 128 + ((kp ^ (ar1 & 7)) << 4));
            b4[0] = *(const intx4*)(sB + br0 * 128 + ((kp ^ (br0 & 7)) << 4));
            b4[1] = *(const intx4*)(sB + br1 * 128 + ((kp ^ (br1 & 7)) << 4));
            sa[0] = sS[kp * 128 + ar0];
            sa[1] = sS[kp * 128 + ar1];
            sb[0] = sS[1024 + kp * 128 + br0];
            sb[1] = sS[1024 + kp * 128 + br1];
#pragma unroll
            for (int mt = 0; mt < 2; ++mt)
#pragma unroll
                for (int nt = 0; nt < 2; ++nt) {
                    intx8 a8 = {a4[mt][0], a4[mt][1], a4[mt][2], a4[mt][3], 0, 0, 0, 0};
                    intx8 b8 = {b4[nt][0], b4[nt][1], b4[nt][2], b4[nt][3], 0, 0, 0, 0};
                    acc[mt][nt] = __builtin_amdgcn_mfma_scale_f32_32x32x64_f8f6f4(
                        a8, b8, acc[mt][nt], 4, 4, 0, sa[mt], 0, sb[nt]);
                }
        }
    }

    // C/D layout (32x32): col = lane&31, row = (reg&3) + 8*(reg>>2) + 4*(lane>>5)
#pragma unroll
    for (int mt = 0; mt < 2; ++mt)
#pragma unroll
        for (int nt = 0; nt < 2; ++nt) {
            const int col = bn0 + wn + nt * 32 + row;
#pragma unroll
            for (int g = 0; g < 4; ++g) {
                const int rw = bm0 + wm + mt * 32 + 8 * g + 4 * h;
#pragma unroll
                for (int q = 0; q < 4; ++q)
                    C[(size_t)(rw + q) * N + col] = acc[mt][nt][4 * g + q];
            }
        }
}

// ---------------------------------------------------------------------------
extern "C" void kernel_launch(void* const* d_in, const int* in_sizes, int n_in,
                              void* d_out, int out_size, void* d_ws, size_t ws_size,
                              hipStream_t stream) {
    const float* x = (const float*)d_in[0];
    const int* wp = (const int*)d_in[1];
    const int* wsc = (const int*)d_in[2];
    float* out = (float*)d_out;

    const int K = 4096;
    const int M = in_sizes[0] / K;            // 4096
    const int N = (in_sizes[1] * 2) / K;      // 4096
    const int kbpr = K / 32;                  // 128
    const int npack = N * K / 2;              // weight packed bytes

    uint32_t* xq   = (uint32_t*)d_ws;                                  // 8 MiB
    uint8_t*  xs   = (uint8_t*)d_ws + (size_t)M * K / 2;               // 512 KiB [m][kb]
    uint8_t*  ws   = xs + (size_t)M * kbpr;                            // 512 KiB [n][kb]
    uint32_t* wrep = (uint32_t*)(ws + (size_t)N * kbpr);               // 8 MiB
    uint8_t*  xs_t = (uint8_t*)(wrep + (size_t)npack / 4);             // 512 KiB [kb][m]
    uint8_t*  ws_t = xs_t + (size_t)M * kbpr;                          // 512 KiB [kb][n]

    const int n4w = npack / 4;
    const int n4s = (N * kbpr) / 4;

    quant_x_kernel<<<(M * K / 4) / 256, 256, 0, stream>>>(x, xq, xs);
    repack_kernel<<<(n4w + n4s + 255) / 256, 256, 0, stream>>>(wp, wrep, n4w,
                                                               wsc, (uint32_t*)ws, n4s);
    dim3 tg(2 * M / 128, kbpr / 32);
    tpose_s_kernel<<<tg, 256, 0, stream>>>(xs, xs_t, ws_t, M, kbpr);

    dim3 grid(N / 128, M / 128);
    gemm_mx_kernel<<<grid, 256, 0, stream>>>((const uint8_t*)xq, (const uint8_t*)wrep,
                                             xs_t, ws_t, out, M, N, K);
}